// Round 1
// baseline (524.518 us; speedup 1.0000x reference)
//
#include <hip/hip_runtime.h>

// Problem constants (fixed by the reference setup_inputs)
constexpr int B  = 8;
constexpr int D  = 64;
constexpr int H  = 384;
constexpr int W  = 512;
constexpr int HW = H * W;          // 196608
constexpr int NP = B * HW;         // 1572864 pixels
constexpr float INV_SPLITS = 1.0f / 6.0f;

// Each thread: 4 consecutive pixels (float4), loops over all D=64 bins.
// NP/4 = 393216 work items = 1536 blocks x 256 threads exactly.
__global__ __launch_bounds__(256)
void sce_main(const float* __restrict__ sim,
              const float* __restrict__ gt,
              double* __restrict__ total_acc,
              unsigned int* __restrict__ count_acc) {
    const int tid = blockIdx.x * blockDim.x + threadIdx.x;
    const int p   = tid * 4;                 // first pixel of this quad
    if (p >= NP) return;

    const float4 g = *reinterpret_cast<const float4*>(gt + p);

    // round(gt / 2): rintf = round-half-to-even, matching jnp.round
    const float gr0 = rintf(g.x * 0.5f);
    const float gr1 = rintf(g.y * 0.5f);
    const float gr2 = rintf(g.z * 0.5f);
    const float gr3 = rintf(g.w * 0.5f);

    // known mask (inf => unknown). For inf, gr=inf -> diff=inf -> P=0, term masked.
    const float m0 = isinf(g.x) ? 0.0f : 1.0f;
    const float m1 = isinf(g.y) ? 0.0f : 1.0f;
    const float m2 = isinf(g.z) ? 0.0f : 1.0f;
    const float m3 = isinf(g.w) ? 0.0f : 1.0f;
    unsigned int cnt = (unsigned int)(m0 + m1 + m2 + m3);

    // flat sim index for pixel p at bin d: p + b*(D-1)*HW + d*HW  (all < 2^27, int ok)
    const int b    = p / HW;
    const int base = p + b * (D - 1) * HW;

    float acc = 0.0f;
    #pragma unroll 4
    for (int d = 0; d < D; ++d) {
        const float4 s = *reinterpret_cast<const float4*>(sim + base + d * HW);
        const float fd = (float)d;

        float df0 = fabsf(gr0 - fd);
        float df1 = fabsf(gr1 - fd);
        float df2 = fabsf(gr2 - fd);
        float df3 = fabsf(gr3 - fd);
        float P0 = (df0 < 6.0f) ? (6.0f - df0) * INV_SPLITS : 0.0f;
        float P1 = (df1 < 6.0f) ? (6.0f - df1) * INV_SPLITS : 0.0f;
        float P2 = (df2 < 6.0f) ? (6.0f - df2) * INV_SPLITS : 0.0f;
        float P3 = (df3 < 6.0f) ? (6.0f - df3) * INV_SPLITS : 0.0f;

        acc += fabsf(s.x - P0) * m0;
        acc += fabsf(s.y - P1) * m1;
        acc += fabsf(s.z - P2) * m2;
        acc += fabsf(s.w - P3) * m3;
    }

    // ---- reduction: wave64 shuffle -> LDS across 4 waves -> global atomics ----
    #pragma unroll
    for (int off = 32; off > 0; off >>= 1) {
        acc += __shfl_down(acc, off, 64);
        cnt += __shfl_down((int)cnt, off, 64);
    }

    __shared__ float  s_sum[4];
    __shared__ unsigned int s_cnt[4];
    const int wave = threadIdx.x >> 6;
    const int lane = threadIdx.x & 63;
    if (lane == 0) { s_sum[wave] = acc; s_cnt[wave] = cnt; }
    __syncthreads();
    if (threadIdx.x == 0) {
        float bs = s_sum[0] + s_sum[1] + s_sum[2] + s_sum[3];
        unsigned int bc = s_cnt[0] + s_cnt[1] + s_cnt[2] + s_cnt[3];
        atomicAdd(total_acc, (double)bs);
        atomicAdd(count_acc, bc);
    }
}

__global__ void sce_final(const double* __restrict__ total_acc,
                          const unsigned int* __restrict__ count_acc,
                          float* __restrict__ out) {
    out[0] = (float)(total_acc[0] / ((double)count_acc[0] * (double)D));
}

extern "C" void kernel_launch(void* const* d_in, const int* in_sizes, int n_in,
                              void* d_out, int out_size, void* d_ws, size_t ws_size,
                              hipStream_t stream) {
    const float* sim = (const float*)d_in[0];
    const float* gt  = (const float*)d_in[1];
    float* out = (float*)d_out;

    double*       total_acc = (double*)d_ws;
    unsigned int* count_acc = (unsigned int*)((char*)d_ws + sizeof(double));

    // ws is re-poisoned to 0xAA before every timed launch — zero it ourselves.
    hipMemsetAsync(d_ws, 0, 16, stream);

    const int items  = NP / 4;          // 393216
    const int block  = 256;
    const int grid   = (items + block - 1) / block;   // 1536
    sce_main<<<grid, block, 0, stream>>>(sim, gt, total_acc, count_acc);
    sce_final<<<1, 1, 0, stream>>>(total_acc, count_acc, out);
}

// Round 2
// 520.483 us; speedup vs baseline: 1.0078x; 1.0078x over previous
//
#include <hip/hip_runtime.h>

// Problem constants (fixed by the reference setup_inputs)
constexpr int B  = 8;
constexpr int D  = 64;
constexpr int H  = 384;
constexpr int W  = 512;
constexpr int HW  = H * W;            // 196608
constexpr int HW4 = HW / 4;           // 49152 float4-quads per plane
constexpr int NQ  = B * D * HW4;      // 25165824 total float4 quads
constexpr int TPB    = 256;
constexpr int BLOCKS = 2048;          // 8 blocks/CU * 256 CUs -> full 32 waves/CU
constexpr int TOT    = BLOCKS * TPB;  // 524288 threads
constexpr int ITERS  = NQ / TOT;      // 48 exactly, no tail
constexpr float INV_SPLITS = 1.0f / 6.0f;

// Flat linear stream over the whole [B,D,H,W] tensor. sim is read exactly
// once in pure sequential order (same access shape as a D2D copy, which the
// poison fills show runs at ~82% HBM peak). gt (6.3 MB) is re-read once per
// d-plane but stays LLC-resident -> no extra HBM traffic.
__global__ __launch_bounds__(TPB)
void sce_main(const float4* __restrict__ sim4,
              const float*  __restrict__ gt,
              float*        __restrict__ psum,
              unsigned int* __restrict__ pcnt) {
    const int tid = blockIdx.x * TPB + threadIdx.x;

    float acc = 0.0f;
    unsigned int cnt = 0;

    #pragma unroll 2
    for (int i = 0; i < ITERS; ++i) {
        const int q     = tid + i * TOT;       // flat quad index, coalesced
        const int plane = q / HW4;             // magic-mul div by 49152
        const int pq    = q - plane * HW4;     // quad index within plane
        const int d     = plane & (D - 1);
        const int b     = plane >> 6;          // plane / D

        const float4 s = sim4[q];
        const float4 g = *reinterpret_cast<const float4*>(gt + b * HW + 4 * pq);

        const float fd = (float)d;

        // round(gt/2), round-half-even matches jnp.round; inf stays inf.
        const float gr0 = rintf(g.x * 0.5f);
        const float gr1 = rintf(g.y * 0.5f);
        const float gr2 = rintf(g.z * 0.5f);
        const float gr3 = rintf(g.w * 0.5f);

        const float m0 = isinf(g.x) ? 0.0f : 1.0f;
        const float m1 = isinf(g.y) ? 0.0f : 1.0f;
        const float m2 = isinf(g.z) ? 0.0f : 1.0f;
        const float m3 = isinf(g.w) ? 0.0f : 1.0f;

        float df0 = fabsf(gr0 - fd);
        float df1 = fabsf(gr1 - fd);
        float df2 = fabsf(gr2 - fd);
        float df3 = fabsf(gr3 - fd);
        // for unknown pixels df=inf -> P=0 and term is masked to 0 anyway
        float P0 = (df0 < 6.0f) ? (6.0f - df0) * INV_SPLITS : 0.0f;
        float P1 = (df1 < 6.0f) ? (6.0f - df1) * INV_SPLITS : 0.0f;
        float P2 = (df2 < 6.0f) ? (6.0f - df2) * INV_SPLITS : 0.0f;
        float P3 = (df3 < 6.0f) ? (6.0f - df3) * INV_SPLITS : 0.0f;

        acc += fabsf(s.x - P0) * m0;
        acc += fabsf(s.y - P1) * m1;
        acc += fabsf(s.z - P2) * m2;
        acc += fabsf(s.w - P3) * m3;

        // count each known pixel exactly once: only on the d==0 plane
        if (d == 0) cnt += (unsigned int)(m0 + m1 + m2 + m3);
    }

    // ---- block reduction: wave64 shuffle -> LDS across 4 waves ----
    #pragma unroll
    for (int off = 32; off > 0; off >>= 1) {
        acc += __shfl_down(acc, off, 64);
        cnt += (unsigned int)__shfl_down((int)cnt, off, 64);
    }

    __shared__ float        s_sum[4];
    __shared__ unsigned int s_cnt[4];
    const int wave = threadIdx.x >> 6;
    const int lane = threadIdx.x & 63;
    if (lane == 0) { s_sum[wave] = acc; s_cnt[wave] = cnt; }
    __syncthreads();
    if (threadIdx.x == 0) {
        psum[blockIdx.x] = s_sum[0] + s_sum[1] + s_sum[2] + s_sum[3];
        pcnt[blockIdx.x] = s_cnt[0] + s_cnt[1] + s_cnt[2] + s_cnt[3];
    }
}

// Single-block reducer over the 2048 per-block partials (double accumulate).
__global__ __launch_bounds__(TPB)
void sce_final(const float*        __restrict__ psum,
               const unsigned int* __restrict__ pcnt,
               float*              __restrict__ out) {
    double a = 0.0;
    double c = 0.0;
    for (int i = threadIdx.x; i < BLOCKS; i += TPB) {
        a += (double)psum[i];
        c += (double)pcnt[i];
    }
    #pragma unroll
    for (int off = 32; off > 0; off >>= 1) {
        a += __shfl_down(a, off, 64);
        c += __shfl_down(c, off, 64);
    }
    __shared__ double s_a[4];
    __shared__ double s_c[4];
    const int wave = threadIdx.x >> 6;
    const int lane = threadIdx.x & 63;
    if (lane == 0) { s_a[wave] = a; s_c[wave] = c; }
    __syncthreads();
    if (threadIdx.x == 0) {
        double ta = s_a[0] + s_a[1] + s_a[2] + s_a[3];
        double tc = s_c[0] + s_c[1] + s_c[2] + s_c[3];
        out[0] = (float)(ta / (tc * (double)D));
    }
}

extern "C" void kernel_launch(void* const* d_in, const int* in_sizes, int n_in,
                              void* d_out, int out_size, void* d_ws, size_t ws_size,
                              hipStream_t stream) {
    const float4* sim4 = (const float4*)d_in[0];
    const float*  gt   = (const float*)d_in[1];
    float* out = (float*)d_out;

    float*        psum = (float*)d_ws;
    unsigned int* pcnt = (unsigned int*)((char*)d_ws + BLOCKS * sizeof(float));

    sce_main<<<BLOCKS, TPB, 0, stream>>>(sim4, gt, psum, pcnt);
    sce_final<<<1, TPB, 0, stream>>>(psum, pcnt, out);
}

// Round 3
// 520.445 us; speedup vs baseline: 1.0078x; 1.0001x over previous
//
#include <hip/hip_runtime.h>

// Problem constants (fixed by the reference setup_inputs)
constexpr int B  = 8;
constexpr int D  = 64;
constexpr int H  = 384;
constexpr int W  = 512;
constexpr int HW  = H * W;            // 196608 pixels per (b,d) plane
constexpr int NP  = B * HW;           // 1572864 pixels
constexpr int NP2 = NP / 2;           // 786432 pixel-pairs -> exactly 100% occupancy
constexpr int TPB    = 256;
constexpr int BLOCKS = NP2 / TPB;     // 3072 blocks (12/CU -> full 32 waves/CU)
constexpr float INV_SPLITS = 1.0f / 6.0f;

// Pixel-major: each thread owns 2 consecutive pixels, reads its gt float2 ONCE,
// then streams the 64 sim bins at stride HW. Total traffic entering L2 is
// ~410 MB (sim once + gt once) vs R2's ~810 MB (gt re-read per bin from LLC).
__global__ __launch_bounds__(TPB, 8)
void sce_main(const float* __restrict__ sim,
              const float* __restrict__ gt,
              float*        __restrict__ psum,
              unsigned int* __restrict__ pcnt) {
    const int tid = blockIdx.x * TPB + threadIdx.x;
    const int p   = tid * 2;                   // first pixel of the pair
    const int b   = (unsigned)p / (unsigned)HW; // magic-mul, once per thread
    const int pp  = p - b * HW;                // offset within plane

    const float2 g = *reinterpret_cast<const float2*>(gt + p);

    // round(gt/2): rintf = round-half-even, matches jnp.round. inf stays inf,
    // which propagates to rc = max(6 - inf, 0) = 0 -> P = 0 -> masked term 0.
    const float gr0 = rintf(g.x * 0.5f);
    const float gr1 = rintf(g.y * 0.5f);
    const float m0 = isinf(g.x) ? 0.0f : 1.0f;
    const float m1 = isinf(g.y) ? 0.0f : 1.0f;
    unsigned int cnt = (unsigned int)(m0 + m1);

    const float* sp = sim + (size_t)b * D * HW + pp;

    float acc = 0.0f;
    #pragma unroll 8
    for (int d = 0; d < D; ++d) {
        const float2 s = *reinterpret_cast<const float2*>(sp + (size_t)d * HW);
        const float fd = (float)d;
        // P = max(0, 6 - |gr - d|) / 6 ; term = |s - P| * m
        float r0 = fmaxf(6.0f - fabsf(gr0 - fd), 0.0f);
        float r1 = fmaxf(6.0f - fabsf(gr1 - fd), 0.0f);
        float t0 = fmaf(r0, INV_SPLITS, -s.x);
        float t1 = fmaf(r1, INV_SPLITS, -s.y);
        acc = fmaf(fabsf(t0), m0, acc);
        acc = fmaf(fabsf(t1), m1, acc);
    }

    // ---- block reduction: wave64 shuffle -> LDS across 4 waves ----
    #pragma unroll
    for (int off = 32; off > 0; off >>= 1) {
        acc += __shfl_down(acc, off, 64);
        cnt += (unsigned int)__shfl_down((int)cnt, off, 64);
    }

    __shared__ float        s_sum[4];
    __shared__ unsigned int s_cnt[4];
    const int wave = threadIdx.x >> 6;
    const int lane = threadIdx.x & 63;
    if (lane == 0) { s_sum[wave] = acc; s_cnt[wave] = cnt; }
    __syncthreads();
    if (threadIdx.x == 0) {
        psum[blockIdx.x] = s_sum[0] + s_sum[1] + s_sum[2] + s_sum[3];
        pcnt[blockIdx.x] = s_cnt[0] + s_cnt[1] + s_cnt[2] + s_cnt[3];
    }
}

// Single-block reducer over the per-block partials (double accumulate).
__global__ __launch_bounds__(TPB)
void sce_final(const float*        __restrict__ psum,
               const unsigned int* __restrict__ pcnt,
               float*              __restrict__ out) {
    double a = 0.0;
    double c = 0.0;
    for (int i = threadIdx.x; i < BLOCKS; i += TPB) {
        a += (double)psum[i];
        c += (double)pcnt[i];
    }
    #pragma unroll
    for (int off = 32; off > 0; off >>= 1) {
        a += __shfl_down(a, off, 64);
        c += __shfl_down(c, off, 64);
    }
    __shared__ double s_a[4];
    __shared__ double s_c[4];
    const int wave = threadIdx.x >> 6;
    const int lane = threadIdx.x & 63;
    if (lane == 0) { s_a[wave] = a; s_c[wave] = c; }
    __syncthreads();
    if (threadIdx.x == 0) {
        double ta = s_a[0] + s_a[1] + s_a[2] + s_a[3];
        double tc = s_c[0] + s_c[1] + s_c[2] + s_c[3];
        out[0] = (float)(ta / (tc * (double)D));
    }
}

extern "C" void kernel_launch(void* const* d_in, const int* in_sizes, int n_in,
                              void* d_out, int out_size, void* d_ws, size_t ws_size,
                              hipStream_t stream) {
    const float* sim = (const float*)d_in[0];
    const float* gt  = (const float*)d_in[1];
    float* out = (float*)d_out;

    float*        psum = (float*)d_ws;
    unsigned int* pcnt = (unsigned int*)((char*)d_ws + BLOCKS * sizeof(float));

    sce_main<<<BLOCKS, TPB, 0, stream>>>(sim, gt, psum, pcnt);
    sce_final<<<1, TPB, 0, stream>>>(psum, pcnt, out);
}